// Round 8
// baseline (2637.957 us; speedup 1.0000x reference)
//
#include <hip/hip_runtime.h>

typedef unsigned int uint;

#define N_NODES 100000
#define E_EDGES 1600000
#define L_LAYERS 3
#define G_GRAPHS 128
#define OUT_F 10
#define BN_EPS 1e-5f

#define NB4 (N_NODES / 4)                 // 25000 int4 chunks
#define SCAN_BLOCKS ((NB4 + 255) / 256)   // 98
#define BSHIFT 7                          // 128-node stripes for XCD ownership
#define CHUNK 2048
#define NCHUNK ((E_EDGES + CHUNK - 1) / CHUNK)   // 782
#define EMAX 2560                         // max edges per 64-row block (mean 1024, sd 32)

// bf16 pack (RTNE) / unpack helpers
__device__ __forceinline__ uint bf_pack(float a, float b) {
    uint ua = __float_as_uint(a);
    ua = (ua + 0x7fffu + ((ua >> 16) & 1u)) >> 16;
    uint ub = __float_as_uint(b);
    ub = (ub + 0x7fffu + ((ub >> 16) & 1u)) >> 16;
    return ua | (ub << 16);
}
__device__ __forceinline__ unsigned short bf1(float a) {
    uint ua = __float_as_uint(a);
    return (unsigned short)((ua + 0x7fffu + ((ua >> 16) & 1u)) >> 16);
}
__device__ __forceinline__ float lo16(uint u) { return __uint_as_float(u << 16); }
__device__ __forceinline__ float hi16(uint u) { return __uint_as_float(u & 0xffff0000u); }

// -------------------- CSR build: degree histogram (int4) -----------------
__global__ __launch_bounds__(256) void deg_kernel(const int* __restrict__ dst,
                                                  int* __restrict__ deg) {
    int i = blockIdx.x * blockDim.x + threadIdx.x;   // E/4 threads
    if (i < E_EDGES / 4) {
        int4 d = reinterpret_cast<const int4*>(dst)[i];
        atomicAdd(&deg[d.x], 1);
        atomicAdd(&deg[d.y], 1);
        atomicAdd(&deg[d.z], 1);
        atomicAdd(&deg[d.w], 1);
    }
}

// -------------------- scan phase A: per-block sums -----------------------
__global__ __launch_bounds__(256) void scanA_kernel(const int* __restrict__ deg,
                                                    int* __restrict__ bsum) {
    __shared__ int red[256];
    int t = threadIdx.x;
    int i4 = blockIdx.x * 256 + t;
    int s = 0;
    if (i4 < NB4) {
        int4 v = reinterpret_cast<const int4*>(deg)[i4];
        s = v.x + v.y + v.z + v.w;
    }
    red[t] = s;
    __syncthreads();
    for (int off = 128; off > 0; off >>= 1) {
        if (t < off) red[t] += red[t + off];
        __syncthreads();
    }
    if (t == 0) bsum[blockIdx.x] = red[0];
}

// -------------------- scan phase B: scan the block sums ------------------
__global__ __launch_bounds__(128) void scanB_kernel(int* __restrict__ bsum,
                                                    int* __restrict__ rowptr) {
    __shared__ int p[128];
    int t = threadIdx.x;
    int v = (t < SCAN_BLOCKS) ? bsum[t] : 0;
    p[t] = v;
    __syncthreads();
    for (int off = 1; off < 128; off <<= 1) {
        int u = (t >= off) ? p[t - off] : 0;
        __syncthreads();
        p[t] += u;
        __syncthreads();
    }
    if (t < SCAN_BLOCKS) bsum[t] = p[t] - v;      // exclusive block offset
    if (t == 127) rowptr[N_NODES] = p[127];       // total
}

// ---------- scan phase C: write rowptr + cursor --------------------------
__global__ __launch_bounds__(256) void scanC_kernel(
    const int* __restrict__ deg, const int* __restrict__ bsum,
    int* __restrict__ rowptr, int* __restrict__ cursor) {
    __shared__ int ts[256];
    int t = threadIdx.x;
    int i4 = blockIdx.x * 256 + t;
    int4 v = make_int4(0, 0, 0, 0);
    if (i4 < NB4) v = reinterpret_cast<const int4*>(deg)[i4];
    int s = v.x + v.y + v.z + v.w;
    ts[t] = s;
    __syncthreads();
    for (int off = 1; off < 256; off <<= 1) {
        int u = (t >= off) ? ts[t - off] : 0;
        __syncthreads();
        ts[t] += u;
        __syncthreads();
    }
    if (i4 < NB4) {
        int base = bsum[blockIdx.x] + ts[t] - s;   // exclusive prefix
        int4 rp;
        rp.x = base;
        rp.y = rp.x + v.x;
        rp.z = rp.y + v.y;
        rp.w = rp.z + v.z;
        reinterpret_cast<int4*>(rowptr)[i4] = rp;
        reinterpret_cast<int4*>(cursor)[i4] = rp;
    }
}

// ------------- CSR fill: XCD-striped scatter ------------------------------
__global__ __launch_bounds__(256) void fill_kernel(
    const int* __restrict__ src, const int* __restrict__ dst,
    int* __restrict__ cursor, int* __restrict__ nbr) {
    int xcd = blockIdx.x & 7;
    int base = (blockIdx.x >> 3) * CHUNK;
    #pragma unroll
    for (int it = 0; it < CHUNK / 256; ++it) {
        int e = base + it * 256 + threadIdx.x;
        if (e < E_EDGES) {
            int d = dst[e];
            if (((d >> BSHIFT) & 7) == xcd) {
                int pos = atomicAdd(&cursor[d], 1);
                nbr[pos] = src[e];
            }
        }
    }
}

// -------------------- x f32 -> bf16 (layer 0 only) ------------------------
__global__ __launch_bounds__(256) void tobf_kernel(const float* __restrict__ x,
                                                   uint* __restrict__ xbf) {
    int i = blockIdx.x * 256 + threadIdx.x;   // N*8 threads, 8 floats each
    if (i < N_NODES * 8) {
        float4 a = reinterpret_cast<const float4*>(x)[i * 2];
        float4 b = reinterpret_cast<const float4*>(x)[i * 2 + 1];
        uint4 o;
        o.x = bf_pack(a.x, a.y);
        o.y = bf_pack(a.z, a.w);
        o.z = bf_pack(b.x, b.y);
        o.w = bf_pack(b.z, b.w);
        reinterpret_cast<uint4*>(xbf)[i] = o;
    }
}

// ---- fused gather(edge-parallel, LDS-atomic) + GEMM1 + BN stats ----------
// agg-tile accumulated in LDS: init with self term, then one edge per lane
// (8 independent uint4 loads, no dependent chains), ds_add_f32 accumulate.
__global__ __launch_bounds__(256) void gemm1_fused_kernel(
    const uint* __restrict__ xbf, const int* __restrict__ rowptr,
    const int* __restrict__ nbr, const float* __restrict__ W1,
    const float* __restrict__ b1, unsigned short* __restrict__ h16,
    float* __restrict__ stats) {
    __shared__ float sA[64][64];
    __shared__ float sW[64][64];
    __shared__ int sRP[65];
    __shared__ unsigned char rowmap[EMAX];
    int tid = threadIdx.x;
    int row0 = blockIdx.x * 64;
    int nrows = N_NODES - row0; if (nrows > 64) nrows = 64;

    for (int i = tid; i < 1024; i += 256)
        reinterpret_cast<float4*>(&sW[0][0])[i] = reinterpret_cast<const float4*>(W1)[i];

    if (tid <= nrows) sRP[tid] = rowptr[row0 + tid];

    const uint4* xb4 = reinterpret_cast<const uint4*>(xbf);

    // init sA with the self term (x_i), f32
    for (int i = tid; i < 512; i += 256) {
        int r = i >> 3, sl = i & 7;
        float4 f0 = make_float4(0.f, 0.f, 0.f, 0.f);
        float4 f1 = make_float4(0.f, 0.f, 0.f, 0.f);
        int gr = row0 + r;
        if (gr < N_NODES) {
            uint4 v = xb4[(size_t)gr * 8 + sl];
            f0 = make_float4(lo16(v.x), hi16(v.x), lo16(v.y), hi16(v.y));
            f1 = make_float4(lo16(v.z), hi16(v.z), lo16(v.w), hi16(v.w));
        }
        *reinterpret_cast<float4*>(&sA[r][sl * 8]) = f0;
        *reinterpret_cast<float4*>(&sA[r][sl * 8 + 4]) = f1;
    }
    __syncthreads();

    int beg = sRP[0];
    int ecnt = sRP[nrows] - beg;

    // rowmap: local edge index -> local row
    if (tid < nrows) {
        int b = sRP[tid] - beg, e = sRP[tid + 1] - beg;
        for (int j = b; j < e; ++j) rowmap[j] = (unsigned char)tid;
    }
    __syncthreads();

    // edge-parallel accumulate into LDS
    for (int j0 = 0; j0 < ecnt; j0 += 256) {
        int j = j0 + tid;
        if (j < ecnt) {
            int s = nbr[beg + j];
            int r = rowmap[j];
            const uint4* p = xb4 + (size_t)s * 8;
            uint4 v0 = p[0], v1 = p[1], v2 = p[2], v3 = p[3];
            uint4 v4 = p[4], v5 = p[5], v6 = p[6], v7 = p[7];
            float* row = &sA[r][0];
            #define ACCU(u, o) atomicAdd(row + (o), lo16(u)); atomicAdd(row + (o) + 1, hi16(u));
            ACCU(v0.x, 0)  ACCU(v0.y, 2)  ACCU(v0.z, 4)  ACCU(v0.w, 6)
            ACCU(v1.x, 8)  ACCU(v1.y, 10) ACCU(v1.z, 12) ACCU(v1.w, 14)
            ACCU(v2.x, 16) ACCU(v2.y, 18) ACCU(v2.z, 20) ACCU(v2.w, 22)
            ACCU(v3.x, 24) ACCU(v3.y, 26) ACCU(v3.z, 28) ACCU(v3.w, 30)
            ACCU(v4.x, 32) ACCU(v4.y, 34) ACCU(v4.z, 36) ACCU(v4.w, 38)
            ACCU(v5.x, 40) ACCU(v5.y, 42) ACCU(v5.z, 44) ACCU(v5.w, 46)
            ACCU(v6.x, 48) ACCU(v6.y, 50) ACCU(v6.z, 52) ACCU(v6.w, 54)
            ACCU(v7.x, 56) ACCU(v7.y, 58) ACCU(v7.z, 60) ACCU(v7.w, 62)
            #undef ACCU
        }
    }
    __syncthreads();

    int cc = tid & 63;
    int rbase = (tid >> 6) * 16;
    float bias = b1[cc];
    float lsum = 0.f, lsq = 0.f;
    float hout[16];
    for (int i = 0; i < 16; ++i) {
        int r = rbase + i;
        float acc = bias;
        #pragma unroll
        for (int k = 0; k < 64; ++k) acc += sA[r][k] * sW[k][cc];
        hout[i] = acc;
    }
    for (int i = 0; i < 16; ++i) {
        int gr = row0 + rbase + i;
        if (gr < N_NODES) {
            h16[(size_t)gr * 64 + cc] = bf1(hout[i]);
            lsum += hout[i];
            lsq += hout[i] * hout[i];
        }
    }
    // reuse sA as reduction scratch (all reads of sA are done)
    __syncthreads();
    float* red = &sA[0][0];
    red[tid] = lsum;
    red[256 + tid] = lsq;
    __syncthreads();
    if (tid < 64) {
        float s = red[tid] + red[tid + 64] + red[tid + 128] + red[tid + 192];
        float q = red[256 + tid] + red[256 + tid + 64] + red[256 + tid + 128] + red[256 + tid + 192];
        unsafeAtomicAdd(&stats[tid], s);
        unsafeAtomicAdd(&stats[64 + tid], q);
    }
}

// -- GEMM2 + pool: xn=relu(bn(h))@W2+b2 ; pooled += xn (f32); xn -> bf16 ---
__global__ __launch_bounds__(256) void gemm2_pool_kernel(
    const unsigned short* __restrict__ h16, const float* __restrict__ stats,
    const float* __restrict__ gamma, const float* __restrict__ beta,
    const float* __restrict__ W2, const float* __restrict__ b2,
    const int* __restrict__ batch, float* __restrict__ pooled,
    unsigned short* __restrict__ xout) {
    __shared__ float sA[64][64];
    __shared__ float sW[64][64];
    int tid = threadIdx.x;
    int row0 = blockIdx.x * 64;

    for (int i = tid; i < 1024; i += 256)
        reinterpret_cast<float4*>(&sW[0][0])[i] = reinterpret_cast<const float4*>(W2)[i];

    // per-thread BN scale/shift for its fixed 8 columns (slice c8)
    int c8 = tid & 7;
    float scv[8], shv[8];
    #pragma unroll
    for (int k = 0; k < 8; ++k) {
        int col = c8 * 8 + k;
        float mu = stats[col] * (1.0f / N_NODES);
        float var = stats[64 + col] * (1.0f / N_NODES) - mu * mu;
        scv[k] = gamma[col] * rsqrtf(var + BN_EPS);
        shv[k] = beta[col] - mu * scv[k];
    }

    const uint4* h4 = reinterpret_cast<const uint4*>(h16);
    for (int i = tid; i < 512; i += 256) {
        int r = i >> 3;                    // (i&7) == c8 since 256 % 8 == 0
        int gr = row0 + r;
        float o[8] = {0.f, 0.f, 0.f, 0.f, 0.f, 0.f, 0.f, 0.f};
        if (gr < N_NODES) {
            uint4 v = h4[(size_t)gr * 8 + c8];
            float f[8] = {lo16(v.x), hi16(v.x), lo16(v.y), hi16(v.y),
                          lo16(v.z), hi16(v.z), lo16(v.w), hi16(v.w)};
            #pragma unroll
            for (int k = 0; k < 8; ++k)
                o[k] = fmaxf(fmaf(f[k], scv[k], shv[k]), 0.f);
        }
        *reinterpret_cast<float4*>(&sA[r][c8 * 8]) = make_float4(o[0], o[1], o[2], o[3]);
        *reinterpret_cast<float4*>(&sA[r][c8 * 8 + 4]) = make_float4(o[4], o[5], o[6], o[7]);
    }
    __syncthreads();

    int c = tid & 63;
    int rbase = (tid >> 6) * 16;
    float bias = b2[c];
    float pacc = 0.f;
    int curb = -1;
    for (int i = 0; i < 16; ++i) {
        int r = rbase + i;
        int gr = row0 + r;
        float acc = bias;
        #pragma unroll
        for (int k = 0; k < 64; ++k) acc += sA[r][k] * sW[k][c];
        if (gr < N_NODES) {
            xout[(size_t)gr * 64 + c] = bf1(acc);
            int b = batch[gr];
            if (b != curb) {
                if (curb >= 0) unsafeAtomicAdd(&pooled[curb * 64 + c], pacc);
                curb = b;
                pacc = 0.f;
            }
            pacc += acc;
        }
    }
    if (curb >= 0) unsafeAtomicAdd(&pooled[curb * 64 + c], pacc);
}

// -------------------- output: score += pooled @ Wout + bout --------------
__global__ void out_kernel(const float* __restrict__ pooled,
                           const float* __restrict__ Wout,
                           const float* __restrict__ bout,
                           float* __restrict__ score) {
    int idx = blockIdx.x * blockDim.x + threadIdx.x;
    if (idx >= G_GRAPHS * OUT_F) return;
    int g = idx / OUT_F;
    int o = idx - g * OUT_F;
    float acc = bout[o];
    #pragma unroll
    for (int k = 0; k < 64; ++k) acc += pooled[g * 64 + k] * Wout[k * OUT_F + o];
    score[idx] += acc;
}

extern "C" void kernel_launch(void* const* d_in, const int* in_sizes, int n_in,
                              void* d_out, int out_size, void* d_ws, size_t ws_size,
                              hipStream_t stream) {
    const float* x     = (const float*)d_in[0];
    const int*   ei    = (const int*)d_in[1];
    const int*   batch = (const int*)d_in[2];
    const float* W1    = (const float*)d_in[3];
    const float* b1    = (const float*)d_in[4];
    const float* gamma = (const float*)d_in[5];
    const float* beta  = (const float*)d_in[6];
    const float* W2    = (const float*)d_in[7];
    const float* b2    = (const float*)d_in[8];
    const float* Wout  = (const float*)d_in[9];
    const float* bout  = (const float*)d_in[10];
    float* out = (float*)d_out;

    unsigned short* H16 = (unsigned short*)d_ws;             // N*64 bf16
    uint*  XBF    = (uint*)(H16 + (size_t)N_NODES * 64);     // N*32 uints (bf16 x2)
    float* stats  = (float*)(XBF + (size_t)N_NODES * 32);    // 128
    float* pooled = stats + 128;                             // G*64 (adjacent)
    int*   deg    = (int*)(pooled + (size_t)G_GRAPHS * 64);  // N
    int*   rowptr = deg + N_NODES;                           // N+4
    int*   cursor = rowptr + N_NODES + 4;                    // N
    int*   bsum   = cursor + N_NODES;                        // SCAN_BLOCKS (pad 128)
    int*   nbr    = bsum + 128;                              // E

    const int* src = ei;
    const int* dst = ei + E_EDGES;

    hipMemsetAsync(d_out, 0, (size_t)G_GRAPHS * OUT_F * sizeof(float), stream);
    hipMemsetAsync(deg, 0, (size_t)N_NODES * sizeof(int), stream);

    deg_kernel<<<(E_EDGES / 4 + 255) / 256, 256, 0, stream>>>(dst, deg);
    scanA_kernel<<<SCAN_BLOCKS, 256, 0, stream>>>(deg, bsum);
    scanB_kernel<<<1, 128, 0, stream>>>(bsum, rowptr);
    scanC_kernel<<<SCAN_BLOCKS, 256, 0, stream>>>(deg, bsum, rowptr, cursor);
    fill_kernel<<<NCHUNK * 8, 256, 0, stream>>>(src, dst, cursor, nbr);
    tobf_kernel<<<(N_NODES * 8 + 255) / 256, 256, 0, stream>>>(x, XBF);

    int nb = (N_NODES + 63) / 64;

    for (int l = 0; l < L_LAYERS; ++l) {
        // stats (128) + pooled (G*64) are adjacent: one memset
        hipMemsetAsync(stats, 0, (128 + (size_t)G_GRAPHS * 64) * sizeof(float), stream);

        gemm1_fused_kernel<<<nb, 256, 0, stream>>>(XBF, rowptr, nbr,
            W1 + l * 64 * 64, b1 + l * 64, H16, stats);
        gemm2_pool_kernel<<<nb, 256, 0, stream>>>(H16, stats,
            gamma + l * 64, beta + l * 64, W2 + l * 64 * 64, b2 + l * 64, batch,
            pooled, XBF ? (unsigned short*)XBF : (unsigned short*)XBF);
        out_kernel<<<(G_GRAPHS * OUT_F + 127) / 128, 128, 0, stream>>>(
            pooled, Wout + l * 64 * OUT_F, bout + l * OUT_F, out);
    }
}

// Round 9
// 484.481 us; speedup vs baseline: 5.4449x; 5.4449x over previous
//
#include <hip/hip_runtime.h>

typedef unsigned int uint;

#define N_NODES 100000
#define E_EDGES 1600000
#define L_LAYERS 3
#define G_GRAPHS 128
#define OUT_F 10
#define BN_EPS 1e-5f

#define NB4 (N_NODES / 4)                 // 25000 int4 chunks
#define SCAN_BLOCKS ((NB4 + 255) / 256)   // 98
#define BSHIFT 7                          // 128-node stripes for XCD ownership
#define CHUNK 2048
#define NCHUNK ((E_EDGES + CHUNK - 1) / CHUNK)   // 782
#define PAD8(d) (((d) + 7) & ~7)

// bf16 pack (RTNE) / unpack helpers
__device__ __forceinline__ uint bf_pack(float a, float b) {
    uint ua = __float_as_uint(a);
    ua = (ua + 0x7fffu + ((ua >> 16) & 1u)) >> 16;
    uint ub = __float_as_uint(b);
    ub = (ub + 0x7fffu + ((ub >> 16) & 1u)) >> 16;
    return ua | (ub << 16);
}
__device__ __forceinline__ unsigned short bf1(float a) {
    uint ua = __float_as_uint(a);
    return (unsigned short)((ua + 0x7fffu + ((ua >> 16) & 1u)) >> 16);
}
__device__ __forceinline__ float lo16(uint u) { return __uint_as_float(u << 16); }
__device__ __forceinline__ float hi16(uint u) { return __uint_as_float(u & 0xffff0000u); }
__device__ __forceinline__ float uw(unsigned short u) { return __uint_as_float(((uint)u) << 16); }

// -------------------- CSR build: degree histogram (int4) -----------------
__global__ __launch_bounds__(256) void deg_kernel(const int* __restrict__ dst,
                                                  int* __restrict__ deg) {
    int i = blockIdx.x * blockDim.x + threadIdx.x;   // E/4 threads
    if (i < E_EDGES / 4) {
        int4 d = reinterpret_cast<const int4*>(dst)[i];
        atomicAdd(&deg[d.x], 1);
        atomicAdd(&deg[d.y], 1);
        atomicAdd(&deg[d.z], 1);
        atomicAdd(&deg[d.w], 1);
    }
}

// -------------------- scan phase A: per-block sums (padded degrees) ------
__global__ __launch_bounds__(256) void scanA_kernel(const int* __restrict__ deg,
                                                    int* __restrict__ bsum) {
    __shared__ int red[256];
    int t = threadIdx.x;
    int i4 = blockIdx.x * 256 + t;
    int s = 0;
    if (i4 < NB4) {
        int4 v = reinterpret_cast<const int4*>(deg)[i4];
        s = PAD8(v.x) + PAD8(v.y) + PAD8(v.z) + PAD8(v.w);
    }
    red[t] = s;
    __syncthreads();
    for (int off = 128; off > 0; off >>= 1) {
        if (t < off) red[t] += red[t + off];
        __syncthreads();
    }
    if (t == 0) bsum[blockIdx.x] = red[0];
}

// -------------------- scan phase B: scan the block sums ------------------
__global__ __launch_bounds__(128) void scanB_kernel(int* __restrict__ bsum,
                                                    int* __restrict__ rowptr) {
    __shared__ int p[128];
    int t = threadIdx.x;
    int v = (t < SCAN_BLOCKS) ? bsum[t] : 0;
    p[t] = v;
    __syncthreads();
    for (int off = 1; off < 128; off <<= 1) {
        int u = (t >= off) ? p[t - off] : 0;
        __syncthreads();
        p[t] += u;
        __syncthreads();
    }
    if (t < SCAN_BLOCKS) bsum[t] = p[t] - v;      // exclusive block offset
    if (t == 127) rowptr[N_NODES] = p[127];       // total (padded)
}

// ---------- scan phase C: write padded rowptr + cursor --------------------
__global__ __launch_bounds__(256) void scanC_kernel(
    const int* __restrict__ deg, const int* __restrict__ bsum,
    int* __restrict__ rowptr, int* __restrict__ cursor) {
    __shared__ int ts[256];
    int t = threadIdx.x;
    int i4 = blockIdx.x * 256 + t;
    int4 v = make_int4(0, 0, 0, 0);
    if (i4 < NB4) v = reinterpret_cast<const int4*>(deg)[i4];
    int4 pv = make_int4(PAD8(v.x), PAD8(v.y), PAD8(v.z), PAD8(v.w));
    int s = pv.x + pv.y + pv.z + pv.w;
    ts[t] = s;
    __syncthreads();
    for (int off = 1; off < 256; off <<= 1) {
        int u = (t >= off) ? ts[t - off] : 0;
        __syncthreads();
        ts[t] += u;
        __syncthreads();
    }
    if (i4 < NB4) {
        int base = bsum[blockIdx.x] + ts[t] - s;   // exclusive prefix
        int4 rp;
        rp.x = base;
        rp.y = rp.x + pv.x;
        rp.z = rp.y + pv.y;
        rp.w = rp.z + pv.z;
        reinterpret_cast<int4*>(rowptr)[i4] = rp;
        reinterpret_cast<int4*>(cursor)[i4] = rp;
    }
}

// ------------- CSR fill: XCD-striped scatter ------------------------------
__global__ __launch_bounds__(256) void fill_kernel(
    const int* __restrict__ src, const int* __restrict__ dst,
    int* __restrict__ cursor, int* __restrict__ nbr) {
    int xcd = blockIdx.x & 7;
    int base = (blockIdx.x >> 3) * CHUNK;
    #pragma unroll
    for (int it = 0; it < CHUNK / 256; ++it) {
        int e = base + it * 256 + threadIdx.x;
        if (e < E_EDGES) {
            int d = dst[e];
            if (((d >> BSHIFT) & 7) == xcd) {
                int pos = atomicAdd(&cursor[d], 1);
                nbr[pos] = src[e];
            }
        }
    }
}

// ---------- pad tail of each segment with sentinel row N ------------------
__global__ __launch_bounds__(256) void pad_kernel(
    const int* __restrict__ rowptr, const int* __restrict__ deg,
    int* __restrict__ nbr) {
    int i = blockIdx.x * 256 + threadIdx.x;
    if (i < N_NODES) {
        int b = rowptr[i] + deg[i];
        int e = rowptr[i + 1];
        for (int j = b; j < e; ++j) nbr[j] = N_NODES;   // zero row
    }
}

// -------------------- x f32 -> bf16 (layer 0 only) ------------------------
__global__ __launch_bounds__(256) void tobf_kernel(const float* __restrict__ x,
                                                   uint* __restrict__ xbf) {
    int i = blockIdx.x * 256 + threadIdx.x;   // N*8 threads, 8 floats each
    if (i < N_NODES * 8) {
        float4 a = reinterpret_cast<const float4*>(x)[i * 2];
        float4 b = reinterpret_cast<const float4*>(x)[i * 2 + 1];
        uint4 o;
        o.x = bf_pack(a.x, a.y);
        o.y = bf_pack(a.z, a.w);
        o.z = bf_pack(b.x, b.y);
        o.w = bf_pack(b.z, b.w);
        reinterpret_cast<uint4*>(xbf)[i] = o;
    }
}

// ------- fused gather(bf16, padded CSR) + GEMM1 + BN stats ----------------
// 8 lanes per row (uint4 = 8 bf16), 8 neighbors in flight, int4 index loads.
__global__ __launch_bounds__(256) void gemm1_fused_kernel(
    const uint* __restrict__ xbf, const int* __restrict__ rowptr,
    const int* __restrict__ nbr, const float* __restrict__ W1,
    const float* __restrict__ b1, unsigned short* __restrict__ h16,
    float* __restrict__ stats) {
    __shared__ float sA[64][64];
    __shared__ unsigned short sWh[64][64];
    int tid = threadIdx.x;
    int row0 = blockIdx.x * 64;

    for (int i = tid; i < 1024; i += 256) {
        float4 w = reinterpret_cast<const float4*>(W1)[i];
        unsigned short* p = &sWh[0][0] + i * 4;
        p[0] = bf1(w.x); p[1] = bf1(w.y); p[2] = bf1(w.z); p[3] = bf1(w.w);
    }

    const uint4* xb4 = reinterpret_cast<const uint4*>(xbf);
    int c8 = tid & 7;        // uint4 slot within row (8 bf16 cols)
    int rslot = tid >> 3;    // 32 rows per pass
    for (int rr = 0; rr < 2; ++rr) {
        int r = rslot + 32 * rr;
        int gr = row0 + r;
        float a0 = 0.f, a1 = 0.f, a2 = 0.f, a3 = 0.f;
        float a4 = 0.f, a5 = 0.f, a6 = 0.f, a7 = 0.f;
        if (gr < N_NODES) {
            uint4 sv = xb4[(size_t)gr * 8 + c8];
            a0 = lo16(sv.x); a1 = hi16(sv.x); a2 = lo16(sv.y); a3 = hi16(sv.y);
            a4 = lo16(sv.z); a5 = hi16(sv.z); a6 = lo16(sv.w); a7 = hi16(sv.w);
            int beg = rowptr[gr], end = rowptr[gr + 1];
            for (int j = beg; j < end; j += 8) {
                int4 ia = *reinterpret_cast<const int4*>(nbr + j);
                int4 ib = *reinterpret_cast<const int4*>(nbr + j + 4);
                uint4 v0 = xb4[(size_t)ia.x * 8 + c8];
                uint4 v1 = xb4[(size_t)ia.y * 8 + c8];
                uint4 v2 = xb4[(size_t)ia.z * 8 + c8];
                uint4 v3 = xb4[(size_t)ia.w * 8 + c8];
                uint4 v4 = xb4[(size_t)ib.x * 8 + c8];
                uint4 v5 = xb4[(size_t)ib.y * 8 + c8];
                uint4 v6 = xb4[(size_t)ib.z * 8 + c8];
                uint4 v7 = xb4[(size_t)ib.w * 8 + c8];
                a0 += lo16(v0.x); a1 += hi16(v0.x); a2 += lo16(v0.y); a3 += hi16(v0.y);
                a4 += lo16(v0.z); a5 += hi16(v0.z); a6 += lo16(v0.w); a7 += hi16(v0.w);
                a0 += lo16(v1.x); a1 += hi16(v1.x); a2 += lo16(v1.y); a3 += hi16(v1.y);
                a4 += lo16(v1.z); a5 += hi16(v1.z); a6 += lo16(v1.w); a7 += hi16(v1.w);
                a0 += lo16(v2.x); a1 += hi16(v2.x); a2 += lo16(v2.y); a3 += hi16(v2.y);
                a4 += lo16(v2.z); a5 += hi16(v2.z); a6 += lo16(v2.w); a7 += hi16(v2.w);
                a0 += lo16(v3.x); a1 += hi16(v3.x); a2 += lo16(v3.y); a3 += hi16(v3.y);
                a4 += lo16(v3.z); a5 += hi16(v3.z); a6 += lo16(v3.w); a7 += hi16(v3.w);
                a0 += lo16(v4.x); a1 += hi16(v4.x); a2 += lo16(v4.y); a3 += hi16(v4.y);
                a4 += lo16(v4.z); a5 += hi16(v4.z); a6 += lo16(v4.w); a7 += hi16(v4.w);
                a0 += lo16(v5.x); a1 += hi16(v5.x); a2 += lo16(v5.y); a3 += hi16(v5.y);
                a4 += lo16(v5.z); a5 += hi16(v5.z); a6 += lo16(v5.w); a7 += hi16(v5.w);
                a0 += lo16(v6.x); a1 += hi16(v6.x); a2 += lo16(v6.y); a3 += hi16(v6.y);
                a4 += lo16(v6.z); a5 += hi16(v6.z); a6 += lo16(v6.w); a7 += hi16(v6.w);
                a0 += lo16(v7.x); a1 += hi16(v7.x); a2 += lo16(v7.y); a3 += hi16(v7.y);
                a4 += lo16(v7.z); a5 += hi16(v7.z); a6 += lo16(v7.w); a7 += hi16(v7.w);
            }
        }
        *reinterpret_cast<float4*>(&sA[r][c8 * 8])     = make_float4(a0, a1, a2, a3);
        *reinterpret_cast<float4*>(&sA[r][c8 * 8 + 4]) = make_float4(a4, a5, a6, a7);
    }
    __syncthreads();

    int cc = tid & 63;
    int rbase = (tid >> 6) * 16;
    float bias = b1[cc];
    float lsum = 0.f, lsq = 0.f;
    float hout[16];
    #pragma unroll 1
    for (int i = 0; i < 16; ++i) hout[i] = bias;
    for (int k = 0; k < 64; ++k) {
        float w = uw(sWh[k][cc]);
        #pragma unroll
        for (int i = 0; i < 16; ++i) hout[i] = fmaf(sA[rbase + i][k], w, hout[i]);
    }
    for (int i = 0; i < 16; ++i) {
        int gr = row0 + rbase + i;
        if (gr < N_NODES) {
            h16[(size_t)gr * 64 + cc] = bf1(hout[i]);
            lsum += hout[i];
            lsq += hout[i] * hout[i];
        }
    }
    // reuse sA as reduction scratch (all reads of sA are done)
    __syncthreads();
    float* red = &sA[0][0];
    red[tid] = lsum;
    red[256 + tid] = lsq;
    __syncthreads();
    if (tid < 64) {
        float s = red[tid] + red[tid + 64] + red[tid + 128] + red[tid + 192];
        float q = red[256 + tid] + red[256 + tid + 64] + red[256 + tid + 128] + red[256 + tid + 192];
        unsafeAtomicAdd(&stats[tid], s);
        unsafeAtomicAdd(&stats[64 + tid], q);
    }
}

// -- GEMM2 + pool: xn=relu(bn(h))@W2+b2 ; pooled += xn (f32); xn -> bf16 ---
__global__ __launch_bounds__(256) void gemm2_pool_kernel(
    const unsigned short* __restrict__ h16, const float* __restrict__ stats,
    const float* __restrict__ gamma, const float* __restrict__ beta,
    const float* __restrict__ W2, const float* __restrict__ b2,
    const int* __restrict__ batch, float* __restrict__ pooled,
    unsigned short* __restrict__ xout) {
    __shared__ float sA[64][64];
    __shared__ unsigned short sWh[64][64];
    int tid = threadIdx.x;
    int row0 = blockIdx.x * 64;

    for (int i = tid; i < 1024; i += 256) {
        float4 w = reinterpret_cast<const float4*>(W2)[i];
        unsigned short* p = &sWh[0][0] + i * 4;
        p[0] = bf1(w.x); p[1] = bf1(w.y); p[2] = bf1(w.z); p[3] = bf1(w.w);
    }

    // per-thread BN scale/shift for its fixed 8 columns (slice c8)
    int c8 = tid & 7;
    float scv[8], shv[8];
    #pragma unroll
    for (int k = 0; k < 8; ++k) {
        int col = c8 * 8 + k;
        float mu = stats[col] * (1.0f / N_NODES);
        float var = stats[64 + col] * (1.0f / N_NODES) - mu * mu;
        scv[k] = gamma[col] * rsqrtf(var + BN_EPS);
        shv[k] = beta[col] - mu * scv[k];
    }

    const uint4* h4 = reinterpret_cast<const uint4*>(h16);
    for (int i = tid; i < 512; i += 256) {
        int r = i >> 3;                    // (i&7) == c8 since 256 % 8 == 0
        int gr = row0 + r;
        float o[8] = {0.f, 0.f, 0.f, 0.f, 0.f, 0.f, 0.f, 0.f};
        if (gr < N_NODES) {
            uint4 v = h4[(size_t)gr * 8 + c8];
            float f[8] = {lo16(v.x), hi16(v.x), lo16(v.y), hi16(v.y),
                          lo16(v.z), hi16(v.z), lo16(v.w), hi16(v.w)};
            #pragma unroll
            for (int k = 0; k < 8; ++k)
                o[k] = fmaxf(fmaf(f[k], scv[k], shv[k]), 0.f);
        }
        *reinterpret_cast<float4*>(&sA[r][c8 * 8]) = make_float4(o[0], o[1], o[2], o[3]);
        *reinterpret_cast<float4*>(&sA[r][c8 * 8 + 4]) = make_float4(o[4], o[5], o[6], o[7]);
    }
    __syncthreads();

    int c = tid & 63;
    int rbase = (tid >> 6) * 16;
    float bias = b2[c];
    float acc[16];
    #pragma unroll 1
    for (int i = 0; i < 16; ++i) acc[i] = bias;
    for (int k = 0; k < 64; ++k) {
        float w = uw(sWh[k][c]);
        #pragma unroll
        for (int i = 0; i < 16; ++i) acc[i] = fmaf(sA[rbase + i][k], w, acc[i]);
    }
    float pacc = 0.f;
    int curb = -1;
    for (int i = 0; i < 16; ++i) {
        int gr = row0 + rbase + i;
        if (gr < N_NODES) {
            xout[(size_t)gr * 64 + c] = bf1(acc[i]);
            int b = batch[gr];
            if (b != curb) {
                if (curb >= 0) unsafeAtomicAdd(&pooled[curb * 64 + c], pacc);
                curb = b;
                pacc = 0.f;
            }
            pacc += acc[i];
        }
    }
    if (curb >= 0) unsafeAtomicAdd(&pooled[curb * 64 + c], pacc);
}

// -------------------- output: score += pooled @ Wout + bout --------------
__global__ void out_kernel(const float* __restrict__ pooled,
                           const float* __restrict__ Wout,
                           const float* __restrict__ bout,
                           float* __restrict__ score) {
    int idx = blockIdx.x * blockDim.x + threadIdx.x;
    if (idx >= G_GRAPHS * OUT_F) return;
    int g = idx / OUT_F;
    int o = idx - g * OUT_F;
    float acc = bout[o];
    #pragma unroll
    for (int k = 0; k < 64; ++k) acc += pooled[g * 64 + k] * Wout[k * OUT_F + o];
    score[idx] += acc;
}

extern "C" void kernel_launch(void* const* d_in, const int* in_sizes, int n_in,
                              void* d_out, int out_size, void* d_ws, size_t ws_size,
                              hipStream_t stream) {
    const float* x     = (const float*)d_in[0];
    const int*   ei    = (const int*)d_in[1];
    const int*   batch = (const int*)d_in[2];
    const float* W1    = (const float*)d_in[3];
    const float* b1    = (const float*)d_in[4];
    const float* gamma = (const float*)d_in[5];
    const float* beta  = (const float*)d_in[6];
    const float* W2    = (const float*)d_in[7];
    const float* b2    = (const float*)d_in[8];
    const float* Wout  = (const float*)d_in[9];
    const float* bout  = (const float*)d_in[10];
    float* out = (float*)d_out;

    unsigned short* H16 = (unsigned short*)d_ws;             // N*64 bf16
    uint*  XBF    = (uint*)(H16 + (size_t)N_NODES * 64);     // (N+1)*32 uints
    float* stats  = (float*)(XBF + (size_t)(N_NODES + 1) * 32);  // 128
    float* pooled = stats + 128;                             // G*64 (adjacent)
    int*   deg    = (int*)(pooled + (size_t)G_GRAPHS * 64);  // N
    int*   rowptr = deg + N_NODES;                           // N+4
    int*   cursor = rowptr + N_NODES + 4;                    // N
    int*   bsum   = cursor + N_NODES;                        // SCAN_BLOCKS (pad 128)
    int*   nbr    = bsum + 128;                              // E + 8N (padded CSR)

    const int* src = ei;
    const int* dst = ei + E_EDGES;

    hipMemsetAsync(d_out, 0, (size_t)G_GRAPHS * OUT_F * sizeof(float), stream);
    hipMemsetAsync(deg, 0, (size_t)N_NODES * sizeof(int), stream);
    hipMemsetAsync(XBF + (size_t)N_NODES * 32, 0, 128, stream);   // sentinel zero row

    deg_kernel<<<(E_EDGES / 4 + 255) / 256, 256, 0, stream>>>(dst, deg);
    scanA_kernel<<<SCAN_BLOCKS, 256, 0, stream>>>(deg, bsum);
    scanB_kernel<<<1, 128, 0, stream>>>(bsum, rowptr);
    scanC_kernel<<<SCAN_BLOCKS, 256, 0, stream>>>(deg, bsum, rowptr, cursor);
    fill_kernel<<<NCHUNK * 8, 256, 0, stream>>>(src, dst, cursor, nbr);
    pad_kernel<<<(N_NODES + 255) / 256, 256, 0, stream>>>(rowptr, deg, nbr);
    tobf_kernel<<<(N_NODES * 8 + 255) / 256, 256, 0, stream>>>(x, XBF);

    int nb = (N_NODES + 63) / 64;

    for (int l = 0; l < L_LAYERS; ++l) {
        // stats (128) + pooled (G*64) are adjacent: one memset
        hipMemsetAsync(stats, 0, (128 + (size_t)G_GRAPHS * 64) * sizeof(float), stream);

        gemm1_fused_kernel<<<nb, 256, 0, stream>>>(XBF, rowptr, nbr,
            W1 + l * 64 * 64, b1 + l * 64, H16, stats);
        gemm2_pool_kernel<<<nb, 256, 0, stream>>>(H16, stats,
            gamma + l * 64, beta + l * 64, W2 + l * 64 * 64, b2 + l * 64, batch,
            pooled, (unsigned short*)XBF);
        out_kernel<<<(G_GRAPHS * OUT_F + 127) / 128, 128, 0, stream>>>(
            pooled, Wout + l * 64 * OUT_F, bout + l * OUT_F, out);
    }
}

// Round 11
// 455.199 us; speedup vs baseline: 5.7952x; 1.0643x over previous
//
#include <hip/hip_runtime.h>

typedef unsigned int uint;
typedef int iv4 __attribute__((ext_vector_type(4)));

#define N_NODES 100000
#define E_EDGES 1600000
#define L_LAYERS 3
#define G_GRAPHS 128
#define OUT_F 10
#define BN_EPS 1e-5f

#define NB4 (N_NODES / 4)                 // 25000 int4 chunks
#define SCAN_BLOCKS ((NB4 + 255) / 256)   // 98
#define BSHIFT 7                          // 128-node stripes for XCD ownership
#define CHUNK 2048
#define NCHUNK ((E_EDGES + CHUNK - 1) / CHUNK)   // 782
#define PAD8(d) (((d) + 7) & ~7)

// bf16 pack (RTNE) / unpack helpers
__device__ __forceinline__ uint bf_pack(float a, float b) {
    uint ua = __float_as_uint(a);
    ua = (ua + 0x7fffu + ((ua >> 16) & 1u)) >> 16;
    uint ub = __float_as_uint(b);
    ub = (ub + 0x7fffu + ((ub >> 16) & 1u)) >> 16;
    return ua | (ub << 16);
}
__device__ __forceinline__ unsigned short bf1(float a) {
    uint ua = __float_as_uint(a);
    return (unsigned short)((ua + 0x7fffu + ((ua >> 16) & 1u)) >> 16);
}
__device__ __forceinline__ float lo16(uint u) { return __uint_as_float(u << 16); }
__device__ __forceinline__ float hi16(uint u) { return __uint_as_float(u & 0xffff0000u); }

// -------------------- CSR build: degree histogram (int4, nt loads) -------
__global__ __launch_bounds__(256) void deg_kernel(const int* __restrict__ dst,
                                                  int* __restrict__ deg) {
    int i = blockIdx.x * blockDim.x + threadIdx.x;   // E/4 threads
    if (i < E_EDGES / 4) {
        iv4 d = __builtin_nontemporal_load(reinterpret_cast<const iv4*>(dst) + i);
        atomicAdd(&deg[d.x], 1);
        atomicAdd(&deg[d.y], 1);
        atomicAdd(&deg[d.z], 1);
        atomicAdd(&deg[d.w], 1);
    }
}

// -------------------- scan phase A: per-block sums (padded degrees) ------
__global__ __launch_bounds__(256) void scanA_kernel(const int* __restrict__ deg,
                                                    int* __restrict__ bsum) {
    __shared__ int red[256];
    int t = threadIdx.x;
    int i4 = blockIdx.x * 256 + t;
    int s = 0;
    if (i4 < NB4) {
        int4 v = reinterpret_cast<const int4*>(deg)[i4];
        s = PAD8(v.x) + PAD8(v.y) + PAD8(v.z) + PAD8(v.w);
    }
    red[t] = s;
    __syncthreads();
    for (int off = 128; off > 0; off >>= 1) {
        if (t < off) red[t] += red[t + off];
        __syncthreads();
    }
    if (t == 0) bsum[blockIdx.x] = red[0];
}

// -------------------- scan phase B: scan the block sums ------------------
__global__ __launch_bounds__(128) void scanB_kernel(int* __restrict__ bsum,
                                                    int* __restrict__ rowptr) {
    __shared__ int p[128];
    int t = threadIdx.x;
    int v = (t < SCAN_BLOCKS) ? bsum[t] : 0;
    p[t] = v;
    __syncthreads();
    for (int off = 1; off < 128; off <<= 1) {
        int u = (t >= off) ? p[t - off] : 0;
        __syncthreads();
        p[t] += u;
        __syncthreads();
    }
    if (t < SCAN_BLOCKS) bsum[t] = p[t] - v;      // exclusive block offset
    if (t == 127) rowptr[N_NODES] = p[127];       // total (padded)
}

// ---------- scan phase C: write padded rowptr + cursor --------------------
__global__ __launch_bounds__(256) void scanC_kernel(
    const int* __restrict__ deg, const int* __restrict__ bsum,
    int* __restrict__ rowptr, int* __restrict__ cursor) {
    __shared__ int ts[256];
    int t = threadIdx.x;
    int i4 = blockIdx.x * 256 + t;
    int4 v = make_int4(0, 0, 0, 0);
    if (i4 < NB4) v = reinterpret_cast<const int4*>(deg)[i4];
    int4 pv = make_int4(PAD8(v.x), PAD8(v.y), PAD8(v.z), PAD8(v.w));
    int s = pv.x + pv.y + pv.z + pv.w;
    ts[t] = s;
    __syncthreads();
    for (int off = 1; off < 256; off <<= 1) {
        int u = (t >= off) ? ts[t - off] : 0;
        __syncthreads();
        ts[t] += u;
        __syncthreads();
    }
    if (i4 < NB4) {
        int base = bsum[blockIdx.x] + ts[t] - s;   // exclusive prefix
        int4 rp;
        rp.x = base;
        rp.y = rp.x + pv.x;
        rp.z = rp.y + pv.y;
        rp.w = rp.z + pv.z;
        reinterpret_cast<int4*>(rowptr)[i4] = rp;
        reinterpret_cast<int4*>(cursor)[i4] = rp;
    }
}

// ------------- CSR fill: XCD-striped scatter, nt streaming reads ----------
__global__ __launch_bounds__(256) void fill_kernel(
    const int* __restrict__ src, const int* __restrict__ dst,
    int* __restrict__ cursor, int* __restrict__ nbr) {
    int xcd = blockIdx.x & 7;
    int base = (blockIdx.x >> 3) * CHUNK;
    #pragma unroll
    for (int it = 0; it < CHUNK / 256; ++it) {
        int e = base + it * 256 + threadIdx.x;
        if (e < E_EDGES) {
            int d = __builtin_nontemporal_load(dst + e);
            if (((d >> BSHIFT) & 7) == xcd) {
                int s = __builtin_nontemporal_load(src + e);
                int pos = atomicAdd(&cursor[d], 1);
                nbr[pos] = s;
            }
        }
    }
}

// ---------- pad tail of each segment with sentinel row N ------------------
__global__ __launch_bounds__(256) void pad_kernel(
    const int* __restrict__ rowptr, const int* __restrict__ deg,
    int* __restrict__ nbr) {
    int i = blockIdx.x * 256 + threadIdx.x;
    if (i < N_NODES) {
        int b = rowptr[i] + deg[i];
        int e = rowptr[i + 1];
        for (int j = b; j < e; ++j) nbr[j] = N_NODES;   // zero row
    }
}

// -------------------- x f32 -> bf16 (layer 0 only) ------------------------
__global__ __launch_bounds__(256) void tobf_kernel(const float* __restrict__ x,
                                                   uint* __restrict__ xbf) {
    int i = blockIdx.x * 256 + threadIdx.x;   // N*8 threads, 8 floats each
    if (i < N_NODES * 8) {
        float4 a = reinterpret_cast<const float4*>(x)[i * 2];
        float4 b = reinterpret_cast<const float4*>(x)[i * 2 + 1];
        uint4 o;
        o.x = bf_pack(a.x, a.y);
        o.y = bf_pack(a.z, a.w);
        o.z = bf_pack(b.x, b.y);
        o.w = bf_pack(b.z, b.w);
        reinterpret_cast<uint4*>(xbf)[i] = o;
    }
}

// ------- fused gather(bf16, padded CSR) + GEMM1(4x4 tile) + BN stats ------
__global__ __launch_bounds__(256) void gemm1_fused_kernel(
    const uint* __restrict__ xbf, const int* __restrict__ rowptr,
    const int* __restrict__ nbr, const float* __restrict__ W1,
    const float* __restrict__ b1, unsigned short* __restrict__ h16,
    float* __restrict__ stats) {
    __shared__ float sA[64][68];                 // +4 pad: 2-way bank alias (free)
    __shared__ unsigned short sWh[64][64];
    int tid = threadIdx.x;
    int row0 = blockIdx.x * 64;

    for (int i = tid; i < 1024; i += 256) {
        float4 w = reinterpret_cast<const float4*>(W1)[i];
        unsigned short* p = &sWh[0][0] + i * 4;
        p[0] = bf1(w.x); p[1] = bf1(w.y); p[2] = bf1(w.z); p[3] = bf1(w.w);
    }

    const uint4* xb4 = reinterpret_cast<const uint4*>(xbf);
    int c8 = tid & 7;        // uint4 slot within row (8 bf16 cols)
    int rslot = tid >> 3;    // 32 rows per pass
    for (int rr = 0; rr < 2; ++rr) {
        int r = rslot + 32 * rr;
        int gr = row0 + r;
        float a0 = 0.f, a1 = 0.f, a2 = 0.f, a3 = 0.f;
        float a4 = 0.f, a5 = 0.f, a6 = 0.f, a7 = 0.f;
        if (gr < N_NODES) {
            uint4 sv = xb4[(size_t)gr * 8 + c8];
            a0 = lo16(sv.x); a1 = hi16(sv.x); a2 = lo16(sv.y); a3 = hi16(sv.y);
            a4 = lo16(sv.z); a5 = hi16(sv.z); a6 = lo16(sv.w); a7 = hi16(sv.w);
            int beg = rowptr[gr], end = rowptr[gr + 1];
            for (int j = beg; j < end; j += 8) {
                int4 ia = *reinterpret_cast<const int4*>(nbr + j);
                int4 ib = *reinterpret_cast<const int4*>(nbr + j + 4);
                uint4 v0 = xb4[(size_t)ia.x * 8 + c8];
                uint4 v1 = xb4[(size_t)ia.y * 8 + c8];
                uint4 v2 = xb4[(size_t)ia.z * 8 + c8];
                uint4 v3 = xb4[(size_t)ia.w * 8 + c8];
                uint4 v4 = xb4[(size_t)ib.x * 8 + c8];
                uint4 v5 = xb4[(size_t)ib.y * 8 + c8];
                uint4 v6 = xb4[(size_t)ib.z * 8 + c8];
                uint4 v7 = xb4[(size_t)ib.w * 8 + c8];
                a0 += lo16(v0.x); a1 += hi16(v0.x); a2 += lo16(v0.y); a3 += hi16(v0.y);
                a4 += lo16(v0.z); a5 += hi16(v0.z); a6 += lo16(v0.w); a7 += hi16(v0.w);
                a0 += lo16(v1.x); a1 += hi16(v1.x); a2 += lo16(v1.y); a3 += hi16(v1.y);
                a4 += lo16(v1.z); a5 += hi16(v1.z); a6 += lo16(v1.w); a7 += hi16(v1.w);
                a0 += lo16(v2.x); a1 += hi16(v2.x); a2 += lo16(v2.y); a3 += hi16(v2.y);
                a4 += lo16(v2.z); a5 += hi16(v2.z); a6 += lo16(v2.w); a7 += hi16(v2.w);
                a0 += lo16(v3.x); a1 += hi16(v3.x); a2 += lo16(v3.y); a3 += hi16(v3.y);
                a4 += lo16(v3.z); a5 += hi16(v3.z); a6 += lo16(v3.w); a7 += hi16(v3.w);
                a0 += lo16(v4.x); a1 += hi16(v4.x); a2 += lo16(v4.y); a3 += hi16(v4.y);
                a4 += lo16(v4.z); a5 += hi16(v4.z); a6 += lo16(v4.w); a7 += hi16(v4.w);
                a0 += lo16(v5.x); a1 += hi16(v5.x); a2 += lo16(v5.y); a3 += hi16(v5.y);
                a4 += lo16(v5.z); a5 += hi16(v5.z); a6 += lo16(v5.w); a7 += hi16(v5.w);
                a0 += lo16(v6.x); a1 += hi16(v6.x); a2 += lo16(v6.y); a3 += hi16(v6.y);
                a4 += lo16(v6.z); a5 += hi16(v6.z); a6 += lo16(v6.w); a7 += hi16(v6.w);
                a0 += lo16(v7.x); a1 += hi16(v7.x); a2 += lo16(v7.y); a3 += hi16(v7.y);
                a4 += lo16(v7.z); a5 += hi16(v7.z); a6 += lo16(v7.w); a7 += hi16(v7.w);
            }
        }
        *reinterpret_cast<float4*>(&sA[r][c8 * 8])     = make_float4(a0, a1, a2, a3);
        *reinterpret_cast<float4*>(&sA[r][c8 * 8 + 4]) = make_float4(a4, a5, a6, a7);
    }
    __syncthreads();

    // 4x4 register-tiled GEMM: thread (rt=tid>>4, ct=tid&15)
    int ct = tid & 15, rt = tid >> 4;
    int cbase = ct * 4, rbase = rt * 4;
    float4 bias = reinterpret_cast<const float4*>(b1)[ct];
    float acc[4][4];
    #pragma unroll
    for (int i = 0; i < 4; ++i) {
        acc[i][0] = bias.x; acc[i][1] = bias.y; acc[i][2] = bias.z; acc[i][3] = bias.w;
    }
    for (int k = 0; k < 64; ++k) {
        float A0 = sA[rbase + 0][k], A1 = sA[rbase + 1][k];
        float A2 = sA[rbase + 2][k], A3 = sA[rbase + 3][k];
        uint2 wp = *reinterpret_cast<const uint2*>(&sWh[k][cbase]);
        float w0 = lo16(wp.x), w1 = hi16(wp.x), w2 = lo16(wp.y), w3 = hi16(wp.y);
        acc[0][0] = fmaf(A0, w0, acc[0][0]); acc[0][1] = fmaf(A0, w1, acc[0][1]);
        acc[0][2] = fmaf(A0, w2, acc[0][2]); acc[0][3] = fmaf(A0, w3, acc[0][3]);
        acc[1][0] = fmaf(A1, w0, acc[1][0]); acc[1][1] = fmaf(A1, w1, acc[1][1]);
        acc[1][2] = fmaf(A1, w2, acc[1][2]); acc[1][3] = fmaf(A1, w3, acc[1][3]);
        acc[2][0] = fmaf(A2, w0, acc[2][0]); acc[2][1] = fmaf(A2, w1, acc[2][1]);
        acc[2][2] = fmaf(A2, w2, acc[2][2]); acc[2][3] = fmaf(A2, w3, acc[2][3]);
        acc[3][0] = fmaf(A3, w0, acc[3][0]); acc[3][1] = fmaf(A3, w1, acc[3][1]);
        acc[3][2] = fmaf(A3, w2, acc[3][2]); acc[3][3] = fmaf(A3, w3, acc[3][3]);
    }

    float csum[4] = {0.f, 0.f, 0.f, 0.f};
    float csq[4]  = {0.f, 0.f, 0.f, 0.f};
    #pragma unroll
    for (int i = 0; i < 4; ++i) {
        int gr = row0 + rbase + i;
        if (gr < N_NODES) {
            uint2 o;
            o.x = bf_pack(acc[i][0], acc[i][1]);
            o.y = bf_pack(acc[i][2], acc[i][3]);
            *reinterpret_cast<uint2*>(&h16[(size_t)gr * 64 + cbase]) = o;
            #pragma unroll
            for (int j = 0; j < 4; ++j) {
                csum[j] += acc[i][j];
                csq[j]  += acc[i][j] * acc[i][j];
            }
        }
    }
    __syncthreads();                     // sA reads done; reuse as scratch
    float* scratch = &sA[0][0];
    #pragma unroll
    for (int j = 0; j < 4; ++j) {
        scratch[rt * 136 + cbase + j]      = csum[j];
        scratch[rt * 136 + 64 + cbase + j] = csq[j];
    }
    __syncthreads();
    if (tid < 64) {
        float s = 0.f, q = 0.f;
        #pragma unroll
        for (int r2 = 0; r2 < 16; ++r2) {
            s += scratch[r2 * 136 + tid];
            q += scratch[r2 * 136 + 64 + tid];
        }
        unsafeAtomicAdd(&stats[tid], s);
        unsafeAtomicAdd(&stats[64 + tid], q);
    }
}

// -- GEMM2(4x4 tile) + pool: xn=relu(bn(h))@W2+b2; pooled += xn; xn->bf16 --
__global__ __launch_bounds__(256) void gemm2_pool_kernel(
    const unsigned short* __restrict__ h16, const float* __restrict__ stats,
    const float* __restrict__ gamma, const float* __restrict__ beta,
    const float* __restrict__ W2, const float* __restrict__ b2,
    const int* __restrict__ batch, float* __restrict__ pooled,
    unsigned short* __restrict__ xout) {
    __shared__ float sA[64][68];
    __shared__ unsigned short sWh[64][64];
    int tid = threadIdx.x;
    int row0 = blockIdx.x * 64;

    for (int i = tid; i < 1024; i += 256) {
        float4 w = reinterpret_cast<const float4*>(W2)[i];
        unsigned short* p = &sWh[0][0] + i * 4;
        p[0] = bf1(w.x); p[1] = bf1(w.y); p[2] = bf1(w.z); p[3] = bf1(w.w);
    }

    // per-thread BN scale/shift for its fixed 8 staging columns
    int c8 = tid & 7;
    float scv[8], shv[8];
    #pragma unroll
    for (int k = 0; k < 8; ++k) {
        int col = c8 * 8 + k;
        float mu = stats[col] * (1.0f / N_NODES);
        float var = stats[64 + col] * (1.0f / N_NODES) - mu * mu;
        scv[k] = gamma[col] * rsqrtf(var + BN_EPS);
        shv[k] = beta[col] - mu * scv[k];
    }

    const uint4* h4 = reinterpret_cast<const uint4*>(h16);
    for (int i = tid; i < 512; i += 256) {
        int r = i >> 3;                    // (i&7) == c8 since 256 % 8 == 0
        int gr = row0 + r;
        float o[8] = {0.f, 0.f, 0.f, 0.f, 0.f, 0.f, 0.f, 0.f};
        if (gr < N_NODES) {
            uint4 v = h4[(size_t)gr * 8 + c8];
            float f[8] = {lo16(v.x), hi16(v.x), lo16(v.y), hi16(v.y),
                          lo16(v.z), hi16(v.z), lo16(v.w), hi16(v.w)};
            #pragma unroll
            for (int k = 0; k < 8; ++k)
                o[k] = fmaxf(fmaf(f[k], scv[k], shv[k]), 0.f);
        }
        *reinterpret_cast<float4*>(&sA[r][c8 * 8]) = make_float4(o[0], o[1], o[2], o[3]);
        *reinterpret_cast<float4*>(&sA[r][c8 * 8 + 4]) = make_float4(o[4], o[5], o[6], o[7]);
    }
    __syncthreads();

    int ct = tid & 15, rt = tid >> 4;
    int cbase = ct * 4, rbase = rt * 4;
    float4 bias = reinterpret_cast<const float4*>(b2)[ct];
    float acc[4][4];
    #pragma unroll
    for (int i = 0; i < 4; ++i) {
        acc[i][0] = bias.x; acc[i][1] = bias.y; acc[i][2] = bias.z; acc[i][3] = bias.w;
    }
    for (int k = 0; k < 64; ++k) {
        float A0 = sA[rbase + 0][k], A1 = sA[rbase + 1][k];
        float A2 = sA[rbase + 2][k], A3 = sA[rbase + 3][k];
        uint2 wp = *reinterpret_cast<const uint2*>(&sWh[k][cbase]);
        float w0 = lo16(wp.x), w1 = hi16(wp.x), w2 = lo16(wp.y), w3 = hi16(wp.y);
        acc[0][0] = fmaf(A0, w0, acc[0][0]); acc[0][1] = fmaf(A0, w1, acc[0][1]);
        acc[0][2] = fmaf(A0, w2, acc[0][2]); acc[0][3] = fmaf(A0, w3, acc[0][3]);
        acc[1][0] = fmaf(A1, w0, acc[1][0]); acc[1][1] = fmaf(A1, w1, acc[1][1]);
        acc[1][2] = fmaf(A1, w2, acc[1][2]); acc[1][3] = fmaf(A1, w3, acc[1][3]);
        acc[2][0] = fmaf(A2, w0, acc[2][0]); acc[2][1] = fmaf(A2, w1, acc[2][1]);
        acc[2][2] = fmaf(A2, w2, acc[2][2]); acc[2][3] = fmaf(A2, w3, acc[2][3]);
        acc[3][0] = fmaf(A3, w0, acc[3][0]); acc[3][1] = fmaf(A3, w1, acc[3][1]);
        acc[3][2] = fmaf(A3, w2, acc[3][2]); acc[3][3] = fmaf(A3, w3, acc[3][3]);
    }

    // write xout (bf16)
    #pragma unroll
    for (int i = 0; i < 4; ++i) {
        int gr = row0 + rbase + i;
        if (gr < N_NODES) {
            uint2 o;
            o.x = bf_pack(acc[i][0], acc[i][1]);
            o.y = bf_pack(acc[i][2], acc[i][3]);
            *reinterpret_cast<uint2*>(&xout[(size_t)gr * 64 + cbase]) = o;
        }
    }

    // pool: single-graph block -> LDS reduce + 1 atomic/col; else run-length
    int lastrow = row0 + 63; if (lastrow >= N_NODES) lastrow = N_NODES - 1;
    int b0 = batch[row0], bL = batch[lastrow];
    if (b0 == bL) {
        float psum[4] = {0.f, 0.f, 0.f, 0.f};
        #pragma unroll
        for (int i = 0; i < 4; ++i) {
            int gr = row0 + rbase + i;
            if (gr < N_NODES) {
                #pragma unroll
                for (int j = 0; j < 4; ++j) psum[j] += acc[i][j];
            }
        }
        __syncthreads();                 // sA reads done; reuse as scratch
        float* scratch = &sA[0][0];
        #pragma unroll
        for (int j = 0; j < 4; ++j) scratch[rt * 68 + cbase + j] = psum[j];
        __syncthreads();
        if (tid < 64) {
            float s = 0.f;
            #pragma unroll
            for (int r2 = 0; r2 < 16; ++r2) s += scratch[r2 * 68 + tid];
            unsafeAtomicAdd(&pooled[b0 * 64 + tid], s);
        }
    } else {
        #pragma unroll
        for (int j = 0; j < 4; ++j) {
            float pacc = 0.f;
            int curb = -1;
            #pragma unroll
            for (int i = 0; i < 4; ++i) {
                int gr = row0 + rbase + i;
                if (gr < N_NODES) {
                    int b = batch[gr];
                    if (b != curb) {
                        if (curb >= 0) unsafeAtomicAdd(&pooled[curb * 64 + cbase + j], pacc);
                        curb = b;
                        pacc = 0.f;
                    }
                    pacc += acc[i][j];
                }
            }
            if (curb >= 0) unsafeAtomicAdd(&pooled[curb * 64 + cbase + j], pacc);
        }
    }
}

// -------------------- output: score += pooled @ Wout + bout --------------
__global__ void out_kernel(const float* __restrict__ pooled,
                           const float* __restrict__ Wout,
                           const float* __restrict__ bout,
                           float* __restrict__ score) {
    int idx = blockIdx.x * blockDim.x + threadIdx.x;
    if (idx >= G_GRAPHS * OUT_F) return;
    int g = idx / OUT_F;
    int o = idx - g * OUT_F;
    float acc = bout[o];
    #pragma unroll
    for (int k = 0; k < 64; ++k) acc += pooled[g * 64 + k] * Wout[k * OUT_F + o];
    score[idx] += acc;
}

extern "C" void kernel_launch(void* const* d_in, const int* in_sizes, int n_in,
                              void* d_out, int out_size, void* d_ws, size_t ws_size,
                              hipStream_t stream) {
    const float* x     = (const float*)d_in[0];
    const int*   ei    = (const int*)d_in[1];
    const int*   batch = (const int*)d_in[2];
    const float* W1    = (const float*)d_in[3];
    const float* b1    = (const float*)d_in[4];
    const float* gamma = (const float*)d_in[5];
    const float* beta  = (const float*)d_in[6];
    const float* W2    = (const float*)d_in[7];
    const float* b2    = (const float*)d_in[8];
    const float* Wout  = (const float*)d_in[9];
    const float* bout  = (const float*)d_in[10];
    float* out = (float*)d_out;

    unsigned short* H16 = (unsigned short*)d_ws;             // N*64 bf16
    uint*  XBF    = (uint*)(H16 + (size_t)N_NODES * 64);     // (N+1)*32 uints
    float* stats  = (float*)(XBF + (size_t)(N_NODES + 1) * 32);  // 128
    float* pooled = stats + 128;                             // G*64 (adjacent)
    int*   deg    = (int*)(pooled + (size_t)G_GRAPHS * 64);  // N
    int*   rowptr = deg + N_NODES;                           // N+4
    int*   cursor = rowptr + N_NODES + 4;                    // N
    int*   bsum   = cursor + N_NODES;                        // SCAN_BLOCKS (pad 128)
    int*   nbr    = bsum + 128;                              // E + 8N (padded CSR)

    const int* src = ei;
    const int* dst = ei + E_EDGES;

    (void)hipMemsetAsync(d_out, 0, (size_t)G_GRAPHS * OUT_F * sizeof(float), stream);
    (void)hipMemsetAsync(deg, 0, (size_t)N_NODES * sizeof(int), stream);
    (void)hipMemsetAsync(XBF + (size_t)N_NODES * 32, 0, 128, stream);   // sentinel zero row

    deg_kernel<<<(E_EDGES / 4 + 255) / 256, 256, 0, stream>>>(dst, deg);
    scanA_kernel<<<SCAN_BLOCKS, 256, 0, stream>>>(deg, bsum);
    scanB_kernel<<<1, 128, 0, stream>>>(bsum, rowptr);
    scanC_kernel<<<SCAN_BLOCKS, 256, 0, stream>>>(deg, bsum, rowptr, cursor);
    fill_kernel<<<NCHUNK * 8, 256, 0, stream>>>(src, dst, cursor, nbr);
    pad_kernel<<<(N_NODES + 255) / 256, 256, 0, stream>>>(rowptr, deg, nbr);
    tobf_kernel<<<(N_NODES * 8 + 255) / 256, 256, 0, stream>>>(x, XBF);

    int nb = (N_NODES + 63) / 64;

    for (int l = 0; l < L_LAYERS; ++l) {
        // stats (128) + pooled (G*64) are adjacent: one memset
        (void)hipMemsetAsync(stats, 0, (128 + (size_t)G_GRAPHS * 64) * sizeof(float), stream);

        gemm1_fused_kernel<<<nb, 256, 0, stream>>>(XBF, rowptr, nbr,
            W1 + l * 64 * 64, b1 + l * 64, H16, stats);
        gemm2_pool_kernel<<<nb, 256, 0, stream>>>(H16, stats,
            gamma + l * 64, beta + l * 64, W2 + l * 64 * 64, b2 + l * 64, batch,
            pooled, (unsigned short*)XBF);
        out_kernel<<<(G_GRAPHS * OUT_F + 127) / 128, 128, 0, stream>>>(
            pooled, Wout + l * 64 * OUT_F, bout + l * OUT_F, out);
    }
}